// Round 1
// baseline (239.277 us; speedup 1.0000x reference)
//
#include <hip/hip_runtime.h>

// Problem constants (match reference)
#define Bsz 32
#define Csz 256
#define Hsz 64
#define Wsz 64
#define BIN 16
// 64 data cols + 4 pad floats: row pitch 68*4=272 B = 17*16 B, so float4 LDS
// stores stay 16B-aligned and consecutive rows start on different banks.
#define LDS_STRIDE 68

// One block per (b,c) plane: 256 threads = the 16x16 output tile.
// Key change vs previous version: instead of 8 scattered global gathers per
// thread (HBM-cold every iteration because the harness's 512MiB poison fills
// evict L2/L3), each block stages the contiguous ROI sub-rectangle
// [y0(0)..y1(15)] x [aligned x-band] of BOTH feature planes into LDS with
// coalesced float4 streams, then bilinear-samples from LDS. Same ~100MB
// distinct footprint, but fetched as sequential streams instead of
// scattered 64B-granule gathers.
__global__ __launch_bounds__(256) void roi_feature_kernel(
    const float* __restrict__ orig,
    const float* __restrict__ lab,
    const float* __restrict__ attk,
    float* __restrict__ out)
{
    __shared__ float lds0[Hsz * LDS_STRIDE];
    __shared__ float lds1[Hsz * LDS_STRIDE];

    const int bc = blockIdx.x;          // b*Csz + c
    const int b  = bc >> 8;
    const int t  = threadIdx.x;
    const int j  = t & (BIN - 1);
    const int i  = t >> 4;

    // lab[b,0,{1,2,3,4}] — uniform per block, L1/sgpr-cached
    const float* lb = lab + b * 5;
    const float l1 = lb[1], l2 = lb[2], l3 = lb[3], l4 = lb[4];

    // ROI bounds (uniform per block). Grid coords are linear in i/j, so the
    // extremes are at the endpoints; identical fp-op order to the per-thread
    // math below => floor() bounds are exact.
    const float xr_a = ((2.0f * (float)(0  - BIN / 2) * l3 / (float)BIN + (l1 * 2.0f - 1.0f) + 1.0f) * (float)Wsz - 1.0f) * 0.5f;
    const float xr_b = ((2.0f * (float)(15 - BIN / 2) * l3 / (float)BIN + (l1 * 2.0f - 1.0f) + 1.0f) * (float)Wsz - 1.0f) * 0.5f;
    const float yr_a = ((2.0f * (float)(0  - BIN / 2) * l4 / (float)BIN + (l2 * 2.0f - 1.0f) + 1.0f) * (float)Hsz - 1.0f) * 0.5f;
    const float yr_b = ((2.0f * (float)(15 - BIN / 2) * l4 / (float)BIN + (l2 * 2.0f - 1.0f) + 1.0f) * (float)Hsz - 1.0f) * 0.5f;

    const int xlo = (int)floorf(fminf(xr_a, xr_b));
    const int xhi = (int)floorf(fmaxf(xr_a, xr_b)) + 1;
    const int ylo = (int)floorf(fminf(yr_a, yr_b));
    const int yhi = (int)floorf(fmaxf(yr_a, yr_b)) + 1;

    // Clamp to the plane; every VALID corner index lies in [xs,xe]x[ys,ye].
    // Invalid corners get weight 0, so their (clamped-into-band) reads only
    // need to hit staged (written, finite) LDS — which they do.
    const int xs = min(max(xlo, 0), Wsz - 1);
    const int xe = min(max(xhi, 0), Wsz - 1);
    const int ys = min(max(ylo, 0), Hsz - 1);
    const int ye = min(max(yhi, 0), Hsz - 1);

    const int c0    = xs & ~3;                  // 16B-aligned column start
    const int c1e   = xe | 3;                   // inclusive, <= 63
    const int nf4   = ((c1e - c0) >> 2) + 1;    // float4 per row: 1..16
    const int nrows = ye - ys + 1;              // 1..64

    const size_t plane = (size_t)bc * (Hsz * Wsz);
    const float* __restrict__ s0 = orig + plane + (ys * Wsz + c0);
    const float* __restrict__ s1 = attk + plane + (ys * Wsz + c0);

    // ---- Stage the ROI band of both planes, coalesced float4 ----
    const int slots = nrows << 4;               // 16 float4-slots per row
    for (int k = t; k < slots; k += 256) {
        const int r = k >> 4;
        const int s = k & 15;
        if (s < nf4) {
            const float4 v0 = *(const float4*)(s0 + r * Wsz + s * 4);
            const float4 v1 = *(const float4*)(s1 + r * Wsz + s * 4);
            *(float4*)&lds0[r * LDS_STRIDE + s * 4] = v0;
            *(float4*)&lds1[r * LDS_STRIDE + s * 4] = v1;
        }
    }
    __syncthreads();

    // ---- Per-thread bilinear sample (EXACT reference arithmetic order) ----
    const float gx = 2.0f * (float)(j - BIN / 2) * l3 / (float)BIN + (l1 * 2.0f - 1.0f);
    const float gy = 2.0f * (float)(i - BIN / 2) * l4 / (float)BIN + (l2 * 2.0f - 1.0f);
    const float xr = ((gx + 1.0f) * (float)Wsz - 1.0f) * 0.5f;
    const float yr = ((gy + 1.0f) * (float)Hsz - 1.0f) * 0.5f;

    const float x0f = floorf(xr);
    const float y0f = floorf(yr);
    const int x0 = (int)x0f;
    const int y0 = (int)y0f;
    const int x1 = x0 + 1;
    const int y1 = y0 + 1;
    const float wx1 = xr - x0f, wx0 = 1.0f - wx1;
    const float wy1 = yr - y0f, wy0 = 1.0f - wy1;

    float acc0 = 0.0f, acc1 = 0.0f;
#pragma unroll
    for (int k = 0; k < 4; ++k) {
        const int xi = (k & 1) ? x1 : x0;
        const int yi = (k & 2) ? y1 : y0;
        const float w = ((k & 1) ? wx1 : wx0) * ((k & 2) ? wy1 : wy0);
        const bool valid = (xi >= 0) && (xi < Wsz) && (yi >= 0) && (yi < Hsz);
        const float wv = valid ? w : 0.0f;
        const int lx = min(max(xi, c0), c1e) - c0;   // valid => == xi - c0
        const int ly = min(max(yi, ys), ye) - ys;    // valid => == yi - ys
        const int off = ly * LDS_STRIDE + lx;
        acc0 += lds0[off] * wv;
        acc1 += lds1[off] * wv;
    }

    const int tid = bc * 256 + t;   // == flat (b,c,i,j), coalesced
    __builtin_nontemporal_store(acc0, out + tid);
    __builtin_nontemporal_store(acc1, out + tid + (size_t)Bsz * Csz * BIN * BIN);
}

extern "C" void kernel_launch(void* const* d_in, const int* in_sizes, int n_in,
                              void* d_out, int out_size, void* d_ws, size_t ws_size,
                              hipStream_t stream) {
    const float* orig = (const float*)d_in[0];
    const float* lab  = (const float*)d_in[1];
    const float* attk = (const float*)d_in[2];
    float* out = (float*)d_out;

    const int blocks = Bsz * Csz;   // 8192 blocks, one (b,c) plane each
    roi_feature_kernel<<<blocks, 256, 0, stream>>>(orig, lab, attk, out);
}

// Round 3
// 235.463 us; speedup vs baseline: 1.0162x; 1.0162x over previous
//
#include <hip/hip_runtime.h>

// Problem constants (match reference)
#define Bsz 32
#define Csz 256
#define Hsz 64
#define Wsz 64
#define BIN 16
// 64 data cols + 4 pad floats: row pitch 68*4=272 B = 17*16 B, so float4 LDS
// stores stay 16B-aligned and consecutive rows start on different banks.
#define LDS_STRIDE 68

// clang ext_vector type: __builtin_nontemporal_load requires a pointer to
// scalar/vector-of-scalar, NOT HIP_vector_type<float,4>.
typedef float f32x4 __attribute__((ext_vector_type(4)));

// One block per (b,c) plane: 256 threads = the 16x16 output tile.
//
// Stage FULL ROWS of the ROI y-band. The y-band rows [ys..ye] are one
// CONTIGUOUS byte range of the plane (ys*256B .. (ye+1)*256B), so the
// staging loop is a pure sequential stream (avg ~8.4KB/plane/block) ->
// near-peak HBM efficiency. The round-1 x-band staging left 116B gaps
// between row segments, which kept DRAM at scattered-granule efficiency
// (~1.6 TB/s) -- same as the round-0 gather version. Fetch bytes rise
// ~76->~138MB but effective BW rises ~4x => kernel ~78us -> ~26-32us.
__global__ __launch_bounds__(256) void roi_feature_kernel(
    const float* __restrict__ orig,
    const float* __restrict__ lab,
    const float* __restrict__ attk,
    float* __restrict__ out)
{
    __shared__ float lds0[Hsz * LDS_STRIDE];
    __shared__ float lds1[Hsz * LDS_STRIDE];

    const int bc = blockIdx.x;          // b*Csz + c
    const int b  = bc >> 8;
    const int t  = threadIdx.x;
    const int j  = t & (BIN - 1);
    const int i  = t >> 4;

    // lab[b,0,{1,2,3,4}] — uniform per block
    const float* lb = lab + b * 5;
    const float l1 = lb[1], l2 = lb[2], l3 = lb[3], l4 = lb[4];

    // ROI y-bounds (uniform per block). y-grid coords are linear & monotone
    // in i, and the endpoint computations below use the IDENTICAL fp-op
    // order as the per-thread math, so [ylo..yhi] exactly brackets every
    // thread's y0/y1. (Monotonicity survives fp rounding: each step of the
    // chain is a monotone fp op in i.)
    const float yr_a = ((2.0f * (float)(0  - BIN / 2) * l4 / (float)BIN + (l2 * 2.0f - 1.0f) + 1.0f) * (float)Hsz - 1.0f) * 0.5f;
    const float yr_b = ((2.0f * (float)(15 - BIN / 2) * l4 / (float)BIN + (l2 * 2.0f - 1.0f) + 1.0f) * (float)Hsz - 1.0f) * 0.5f;

    const int ylo = (int)floorf(fminf(yr_a, yr_b));
    const int yhi = (int)floorf(fmaxf(yr_a, yr_b)) + 1;

    // Clamp to the plane; every VALID corner's y lies in [ys,ye]. Invalid
    // corners get weight 0; their clamped reads hit staged (finite) LDS.
    const int ys = min(max(ylo, 0), Hsz - 1);
    const int ye = min(max(yhi, 0), Hsz - 1);
    const int nrows = ye - ys + 1;              // 1..64

    const size_t plane = (size_t)bc * (Hsz * Wsz);
    const float* __restrict__ s0 = orig + plane + ys * Wsz;
    const float* __restrict__ s1 = attk + plane + ys * Wsz;

    // ---- Stage full rows ys..ye of both planes: one contiguous stream each.
    // Consecutive threads read consecutive 16B; a wave covers 1KB of
    // contiguous address space per instruction.
    const int slots = nrows << 4;               // 16 float4-slots per row
    for (int k = t; k < slots; k += 256) {
        const int r = k >> 4;
        const int s = k & 15;
        const f32x4 v0 = __builtin_nontemporal_load((const f32x4*)(s0 + r * Wsz + s * 4));
        const f32x4 v1 = __builtin_nontemporal_load((const f32x4*)(s1 + r * Wsz + s * 4));
        *(f32x4*)&lds0[r * LDS_STRIDE + s * 4] = v0;
        *(f32x4*)&lds1[r * LDS_STRIDE + s * 4] = v1;
    }
    __syncthreads();

    // ---- Per-thread bilinear sample (EXACT reference arithmetic order) ----
    const float gx = 2.0f * (float)(j - BIN / 2) * l3 / (float)BIN + (l1 * 2.0f - 1.0f);
    const float gy = 2.0f * (float)(i - BIN / 2) * l4 / (float)BIN + (l2 * 2.0f - 1.0f);
    const float xr = ((gx + 1.0f) * (float)Wsz - 1.0f) * 0.5f;
    const float yr = ((gy + 1.0f) * (float)Hsz - 1.0f) * 0.5f;

    const float x0f = floorf(xr);
    const float y0f = floorf(yr);
    const int x0 = (int)x0f;
    const int y0 = (int)y0f;
    const int x1 = x0 + 1;
    const int y1 = y0 + 1;
    const float wx1 = xr - x0f, wx0 = 1.0f - wx1;
    const float wy1 = yr - y0f, wy0 = 1.0f - wy1;

    float acc0 = 0.0f, acc1 = 0.0f;
#pragma unroll
    for (int k = 0; k < 4; ++k) {
        const int xi = (k & 1) ? x1 : x0;
        const int yi = (k & 2) ? y1 : y0;
        const float w = ((k & 1) ? wx1 : wx0) * ((k & 2) ? wy1 : wy0);
        const bool valid = (xi >= 0) && (xi < Wsz) && (yi >= 0) && (yi < Hsz);
        const float wv = valid ? w : 0.0f;
        const int lx = min(max(xi, 0), Wsz - 1);     // full rows staged
        const int ly = min(max(yi, ys), ye) - ys;    // valid => == yi - ys
        const int off = ly * LDS_STRIDE + lx;
        acc0 += lds0[off] * wv;
        acc1 += lds1[off] * wv;
    }

    const int tid = bc * 256 + t;   // == flat (b,c,i,j), coalesced
    __builtin_nontemporal_store(acc0, out + tid);
    __builtin_nontemporal_store(acc1, out + tid + (size_t)Bsz * Csz * BIN * BIN);
}

extern "C" void kernel_launch(void* const* d_in, const int* in_sizes, int n_in,
                              void* d_out, int out_size, void* d_ws, size_t ws_size,
                              hipStream_t stream) {
    const float* orig = (const float*)d_in[0];
    const float* lab  = (const float*)d_in[1];
    const float* attk = (const float*)d_in[2];
    float* out = (float*)d_out;

    const int blocks = Bsz * Csz;   // 8192 blocks, one (b,c) plane each
    roi_feature_kernel<<<blocks, 256, 0, stream>>>(orig, lab, attk, out);
}